// Round 1
// baseline (3116.625 us; speedup 1.0000x reference)
//
#include <hip/hip_runtime.h>

#define D 128
#define TM 128
#define KT 32

// Accumulate x[src] into h[rel][dst] for rel in [r0, r1). 32 threads per edge.
__global__ __launch_bounds__(256) void scatter_kernel(
    const float* __restrict__ x, const int* __restrict__ src,
    const int* __restrict__ dst, const int* __restrict__ rel,
    float* __restrict__ h, int E, int N, int r0, int r1) {
  int tid = blockIdx.x * blockDim.x + threadIdx.x;
  int e = tid >> 5;
  if (e >= E) return;
  int r = rel[e];
  if (r < r0 || r >= r1) return;
  int lane = tid & 31;
  int s = src[e];
  int d0 = dst[e];
  const float4 v = *reinterpret_cast<const float4*>(x + (size_t)s * D + lane * 4);
  float* hp = h + ((size_t)(r - r0) * N + (size_t)d0) * D + lane * 4;
  unsafeAtomicAdd(hp + 0, v.x);
  unsafeAtomicAdd(hp + 1, v.y);
  unsafeAtomicAdd(hp + 2, v.z);
  unsafeAtomicAdd(hp + 3, v.w);
}

// Fallback (tiny workspace): per-edge message x[src] @ W[rel] scattered to agg[dst].
__global__ __launch_bounds__(256) void edge_msg_kernel(
    const float* __restrict__ x, const int* __restrict__ src,
    const int* __restrict__ dst, const int* __restrict__ rel,
    const float* __restrict__ W, float* __restrict__ agg, int E, int N) {
  int e = blockIdx.x * 4 + (threadIdx.x >> 6);
  if (e >= E) return;
  int lane = threadIdx.x & 63;
  int s = src[e], d0 = dst[e], r = rel[e];
  const float* Wr = W + (size_t)r * D * D;
  const float* xs = x + (size_t)s * D;
  float m0 = 0.f, m1 = 0.f;
  for (int k = 0; k < D; ++k) {
    float xk = xs[k];
    m0 += xk * Wr[(size_t)k * D + lane];
    m1 += xk * Wr[(size_t)k * D + lane + 64];
  }
  unsafeAtomicAdd(agg + (size_t)d0 * D + lane, m0);
  unsafeAtomicAdd(agg + (size_t)d0 * D + lane + 64, m1);
}

// out = [relu]( sum_{m<RB} h[m] @ W[m]  (+ x @ SW)  (+ aggin)  (+ bias) )
// Tile: TM(128) rows x D(128) cols per block, 256 threads, 8x8 per thread.
__global__ __launch_bounds__(256) void gemm_kernel(
    const float* __restrict__ hbase, int RB,
    const float* __restrict__ Wbase,
    const float* __restrict__ xin, const float* __restrict__ SW,
    const float* __restrict__ aggin,
    const float* __restrict__ bias, int do_final,
    float* __restrict__ outp, int N) {
  __shared__ float As[KT][TM + 4];  // transposed: As[k][row]
  __shared__ float Bs[KT][D + 4];   // Bs[k][col]

  const int tid = threadIdx.x;
  const int tx = tid & 15;   // col group: cols tx*8 .. tx*8+7
  const int ty = tid >> 4;   // row group: rows ty*8 .. ty*8+7
  const int row0 = blockIdx.x * TM;

  float acc[8][8];
#pragma unroll
  for (int i = 0; i < 8; ++i)
#pragma unroll
    for (int j = 0; j < 8; ++j) acc[i][j] = 0.f;

  const int nmats = RB + (SW != nullptr ? 1 : 0);
  for (int m = 0; m < nmats; ++m) {
    const float* A = (m < RB) ? (hbase + (size_t)m * N * D) : xin;
    const float* B = (m < RB) ? (Wbase + (size_t)m * D * D) : SW;
    for (int kt = 0; kt < D; kt += KT) {
      // stage A tile (TM x KT), transposed into As
#pragma unroll
      for (int i = 0; i < 4; ++i) {
        int q = tid + i * 256;      // 0..1023
        int r = q >> 3;             // row 0..127
        int kp = (q & 7) * 4;       // k offset 0..28
        int grow = row0 + r;
        float4 v = make_float4(0.f, 0.f, 0.f, 0.f);
        if (grow < N) v = *reinterpret_cast<const float4*>(A + (size_t)grow * D + kt + kp);
        As[kp + 0][r] = v.x;
        As[kp + 1][r] = v.y;
        As[kp + 2][r] = v.z;
        As[kp + 3][r] = v.w;
      }
      // stage B tile (KT x D)
#pragma unroll
      for (int i = 0; i < 4; ++i) {
        int q = tid + i * 256;      // 0..1023
        int rrow = q >> 5;          // 0..31
        int c = (q & 31) * 4;       // 0..124
        float4 v = *reinterpret_cast<const float4*>(B + (size_t)(kt + rrow) * D + c);
        *reinterpret_cast<float4*>(&Bs[rrow][c]) = v;
      }
      __syncthreads();
#pragma unroll
      for (int kk = 0; kk < KT; ++kk) {
        float4 a0 = *reinterpret_cast<const float4*>(&As[kk][ty * 8]);
        float4 a1 = *reinterpret_cast<const float4*>(&As[kk][ty * 8 + 4]);
        float4 b0 = *reinterpret_cast<const float4*>(&Bs[kk][tx * 8]);
        float4 b1 = *reinterpret_cast<const float4*>(&Bs[kk][tx * 8 + 4]);
        float av[8] = {a0.x, a0.y, a0.z, a0.w, a1.x, a1.y, a1.z, a1.w};
        float bv[8] = {b0.x, b0.y, b0.z, b0.w, b1.x, b1.y, b1.z, b1.w};
#pragma unroll
        for (int i = 0; i < 8; ++i)
#pragma unroll
          for (int j = 0; j < 8; ++j) acc[i][j] += av[i] * bv[j];
      }
      __syncthreads();
    }
  }

  // epilogue
  float4 bb0 = make_float4(0.f, 0.f, 0.f, 0.f), bb1 = bb0;
  if (do_final) {
    bb0 = *reinterpret_cast<const float4*>(bias + tx * 8);
    bb1 = *reinterpret_cast<const float4*>(bias + tx * 8 + 4);
  }
#pragma unroll
  for (int i = 0; i < 8; ++i) {
    int grow = row0 + ty * 8 + i;
    if (grow >= N) continue;
    size_t off = (size_t)grow * D + tx * 8;
    float4 r0v = make_float4(acc[i][0], acc[i][1], acc[i][2], acc[i][3]);
    float4 r1v = make_float4(acc[i][4], acc[i][5], acc[i][6], acc[i][7]);
    if (aggin) {
      float4 g0 = *reinterpret_cast<const float4*>(aggin + off);
      float4 g1 = *reinterpret_cast<const float4*>(aggin + off + 4);
      r0v.x += g0.x; r0v.y += g0.y; r0v.z += g0.z; r0v.w += g0.w;
      r1v.x += g1.x; r1v.y += g1.y; r1v.z += g1.z; r1v.w += g1.w;
    }
    if (do_final) {
      r0v.x = fmaxf(r0v.x + bb0.x, 0.f);
      r0v.y = fmaxf(r0v.y + bb0.y, 0.f);
      r0v.z = fmaxf(r0v.z + bb0.z, 0.f);
      r0v.w = fmaxf(r0v.w + bb0.w, 0.f);
      r1v.x = fmaxf(r1v.x + bb1.x, 0.f);
      r1v.y = fmaxf(r1v.y + bb1.y, 0.f);
      r1v.z = fmaxf(r1v.z + bb1.z, 0.f);
      r1v.w = fmaxf(r1v.w + bb1.w, 0.f);
    }
    *reinterpret_cast<float4*>(outp + off) = r0v;
    *reinterpret_cast<float4*>(outp + off + 4) = r1v;
  }
}

extern "C" void kernel_launch(void* const* d_in, const int* in_sizes, int n_in,
                              void* d_out, int out_size, void* d_ws, size_t ws_size,
                              hipStream_t stream) {
  const float* emb = (const float*)d_in[0];
  const float* W1  = (const float*)d_in[1];
  const float* SL1 = (const float*)d_in[2];
  const float* B1  = (const float*)d_in[3];
  const float* W2  = (const float*)d_in[4];
  const float* SL2 = (const float*)d_in[5];
  const float* B2  = (const float*)d_in[6];
  const int* eidx  = (const int*)d_in[7];
  const int* etyp  = (const int*)d_in[8];
  const int N = in_sizes[0] / D;
  const int R = in_sizes[1] / (D * D);
  const int E = in_sizes[8];
  const int* srcp = eidx;
  const int* dstp = eidx + E;
  float* outp = (float*)d_out;

  const size_t nd = (size_t)N * D;
  const size_t wsf = ws_size / sizeof(float);

  float* x1 = (float*)d_ws;  // layer-1 activations [N][D]
  float* agg = nullptr;
  float* hbuf = nullptr;
  int RB = 0;
  if (wsf >= nd * (size_t)(R + 1)) {
    RB = R;                       // single pass: x1 + R relation buffers
    hbuf = x1 + nd;
  } else if (wsf >= nd * 3) {
    agg = x1 + nd;                // multi-pass: x1 + agg + RB relation buffers
    hbuf = agg + nd;
    RB = (int)((wsf - 2 * nd) / nd);
    if (RB > R) RB = R;
  }

  const int sc_blocks = (int)(((size_t)E * 32 + 255) / 256);
  const int gm_blocks = (N + TM - 1) / TM;
  const int em_blocks = (int)((E + 3) / 4);

  auto layer = [&](const float* xin, const float* W, const float* SW,
                   const float* bias, float* xout) {
    if (RB >= 1) {
      for (int r0 = 0; r0 < R; r0 += RB) {
        const int rbp = (R - r0 < RB) ? (R - r0) : RB;
        hipMemsetAsync(hbuf, 0, (size_t)rbp * nd * sizeof(float), stream);
        scatter_kernel<<<sc_blocks, 256, 0, stream>>>(xin, srcp, dstp, etyp,
                                                      hbuf, E, N, r0, r0 + rbp);
        const bool first = (r0 == 0);
        const bool last  = (r0 + rbp >= R);
        gemm_kernel<<<gm_blocks, 256, 0, stream>>>(
            hbuf, rbp, W + (size_t)r0 * D * D,
            first ? xin : nullptr, first ? SW : nullptr,
            first ? nullptr : agg, bias, last ? 1 : 0,
            last ? xout : agg, N);
      }
    } else {
      // minimal-workspace fallback: direct per-edge messages into xout (as agg)
      hipMemsetAsync(xout, 0, nd * sizeof(float), stream);
      edge_msg_kernel<<<em_blocks, 256, 0, stream>>>(xin, srcp, dstp, etyp, W,
                                                     xout, E, N);
      gemm_kernel<<<gm_blocks, 256, 0, stream>>>(nullptr, 0, nullptr, xin, SW,
                                                 xout, bias, 1, xout, N);
    }
  };

  layer(emb, W1, SL1, B1, x1);
  layer(x1, W2, SL2, B2, outp);
}

// Round 2
// 518.301 us; speedup vs baseline: 6.0132x; 6.0132x over previous
//
#include <hip/hip_runtime.h>

#define D 128
#define KT_TOT 1152   // (R+1)*D with R=8
#define BM 128
#define BK 64

typedef __attribute__((ext_vector_type(8))) short short8;
typedef __attribute__((ext_vector_type(4))) float f32x4;

typedef const void __attribute__((address_space(1))) gvoid_t;
typedef void __attribute__((address_space(3))) lvoid_t;

__device__ inline unsigned short f2bf(float f) {
  unsigned u = __builtin_bit_cast(unsigned, f);
  u += 0x7FFFu + ((u >> 16) & 1u);
  return (unsigned short)(u >> 16);
}

__device__ inline void gload16(const void* g, void* l) {
  __builtin_amdgcn_global_load_lds((gvoid_t*)g, (lvoid_t*)l, 16, 0, 0);
}

// Zero the h-region (cols 0..1023) of Abuf[N][KT_TOT] bf16. 128 x 16B chunks/row.
__global__ __launch_bounds__(256) void zero_h(unsigned short* __restrict__ h, long total) {
  int4 z = make_int4(0, 0, 0, 0);
  for (long i = (long)blockIdx.x * 256 + threadIdx.x; i < total;
       i += (long)gridDim.x * 256) {
    long row = i >> 7;
    int j = (int)(i & 127);
    *reinterpret_cast<int4*>(reinterpret_cast<char*>(h) + row * (KT_TOT * 2) + j * 16) = z;
  }
}

// Abuf block 8 (cols 1024..1151) = bf16(x f32). dst = Abuf + 1024.
__global__ __launch_bounds__(256) void cvt_x(const float* __restrict__ x,
                                             unsigned short* __restrict__ dst, int N) {
  long i = (long)blockIdx.x * 256 + threadIdx.x;  // over N*32 float4 chunks
  if (i >= (long)N * 32) return;
  long row = i >> 5;
  int j = (int)(i & 31);
  float4 v = reinterpret_cast<const float4*>(x + row * D)[j];
  unsigned lo = (unsigned)f2bf(v.x) | ((unsigned)f2bf(v.y) << 16);
  unsigned hi = (unsigned)f2bf(v.z) | ((unsigned)f2bf(v.w) << 16);
  uint2 pk = make_uint2(lo, hi);
  *reinterpret_cast<uint2*>(dst + row * KT_TOT + j * 4) = pk;
}

// Bt[col][k] bf16: k<1024 -> W[k>>7][k&127][col]; else SW[k&127][col].
__global__ __launch_bounds__(256) void wcvt(const float* __restrict__ W,
                                            const float* __restrict__ SW,
                                            unsigned short* __restrict__ Bt) {
  int idx = blockIdx.x * 256 + threadIdx.x;
  if (idx >= D * KT_TOT) return;
  int col = idx / KT_TOT;
  int k = idx - col * KT_TOT;
  float v = (k < KT_TOT - D) ? W[(((k >> 7) * D) + (k & 127)) * D + col]
                             : SW[(k & 127) * D + col];
  Bt[(size_t)col * KT_TOT + k] = f2bf(v);
}

// Per edge: 64 lanes, lane l handles elements 2l,2l+1. Packed bf16 atomic add
// into h[dst][rel*128 + 2l..]. xf: f32 source (layer 1) or xb: bf16 source
// with row stride KT_TOT (layer 2, = Abuf+1024).
__global__ __launch_bounds__(256) void scatter_pk(
    const float* __restrict__ xf, const unsigned short* __restrict__ xb,
    const int* __restrict__ src, const int* __restrict__ dst,
    const int* __restrict__ rel, unsigned short* __restrict__ h, int E) {
  int e = blockIdx.x * 4 + (threadIdx.x >> 6);
  if (e >= E) return;
  int lane = threadIdx.x & 63;
  int s = src[e], d0 = dst[e], r = rel[e];
  unsigned pk;
  if (xf) {
    float2 v = *reinterpret_cast<const float2*>(xf + (size_t)s * D + 2 * lane);
    pk = (unsigned)f2bf(v.x) | ((unsigned)f2bf(v.y) << 16);
  } else {
    pk = *reinterpret_cast<const unsigned*>(xb + (size_t)s * KT_TOT + 2 * lane);
  }
  unsigned short* addr = h + (size_t)d0 * KT_TOT + r * D + 2 * lane;
  asm volatile("global_atomic_pk_add_bf16 %0, %1, off" ::"v"(addr), "v"(pk)
               : "memory");
}

// out = relu(Abuf[N][KT_TOT] @ B[KT_TOT][D] + bias). B given transposed: Bt[col][k].
// 128x128 tile / block, 4 waves (2x2 of 64x64), mfma 16x16x32 bf16.
// XOR-swizzled LDS (T2): phys (r,pb) holds logical (r, pb ^ ((r&7)<<4)).
__global__ __launch_bounds__(256) void gemm_mfma(
    const unsigned short* __restrict__ Abuf, const unsigned short* __restrict__ Bt,
    const float* __restrict__ bias, float* __restrict__ outp,
    unsigned short* __restrict__ wb,  // bf16 write target (= Abuf+1024) or null
    int N) {
  __shared__ short8 ldsv[2048];  // 32 KB: As 16KB | Bs 16KB
  char* As = reinterpret_cast<char*>(ldsv);
  char* Bs = As + 16384;

  const int tid = threadIdx.x;
  const int wave = tid >> 6;
  const int lane = tid & 63;
  const int wm = wave >> 1, wn = wave & 1;
  const int row0 = blockIdx.x * BM;
  const int l15 = lane & 15, lq = lane >> 4;

  f32x4 acc[4][4];
#pragma unroll
  for (int m = 0; m < 4; ++m)
#pragma unroll
    for (int n = 0; n < 4; ++n)
#pragma unroll
      for (int q = 0; q < 4; ++q) acc[m][n][q] = 0.f;

  // staging geometry (constant across k-steps)
  int st_r[4], st_lb[4], st_chunk[4];
#pragma unroll
  for (int i = 0; i < 4; ++i) {
    int chunk = i * 4 + wave;
    int c = chunk * 64 + lane;
    int r = c >> 3;
    int pb = (c & 7) << 4;
    st_chunk[i] = chunk;
    st_r[i] = r;
    st_lb[i] = pb ^ ((r & 7) << 4);
  }

  for (int kt = 0; kt < KT_TOT; kt += BK) {
#pragma unroll
    for (int i = 0; i < 4; ++i) {
      int r = st_r[i];
      int grow = row0 + r;
      if (grow >= N) grow = N - 1;
      const char* ga = reinterpret_cast<const char*>(Abuf + (size_t)grow * KT_TOT + kt) + st_lb[i];
      gload16(ga, As + st_chunk[i] * 1024);
      const char* gb = reinterpret_cast<const char*>(Bt + (size_t)r * KT_TOT + kt) + st_lb[i];
      gload16(gb, Bs + st_chunk[i] * 1024);
    }
    __syncthreads();

    short8 af[4][2], bfg[4][2];
#pragma unroll
    for (int m = 0; m < 4; ++m)
#pragma unroll
      for (int kq = 0; kq < 2; ++kq) {
        int r = wm * 64 + m * 16 + l15;
        int pbyte = (kq * 64 + lq * 16) ^ ((r & 7) << 4);
        af[m][kq] = *reinterpret_cast<const short8*>(As + r * 128 + pbyte);
      }
#pragma unroll
    for (int n = 0; n < 4; ++n)
#pragma unroll
      for (int kq = 0; kq < 2; ++kq) {
        int r = wn * 64 + n * 16 + l15;
        int pbyte = (kq * 64 + lq * 16) ^ ((r & 7) << 4);
        bfg[n][kq] = *reinterpret_cast<const short8*>(Bs + r * 128 + pbyte);
      }
#pragma unroll
    for (int m = 0; m < 4; ++m)
#pragma unroll
      for (int n = 0; n < 4; ++n) {
        acc[m][n] = __builtin_amdgcn_mfma_f32_16x16x32_bf16(af[m][0], bfg[n][0], acc[m][n], 0, 0, 0);
        acc[m][n] = __builtin_amdgcn_mfma_f32_16x16x32_bf16(af[m][1], bfg[n][1], acc[m][n], 0, 0, 0);
      }
    __syncthreads();
  }

  // epilogue: C/D layout col = lane&15, row = (lane>>4)*4 + reg
#pragma unroll
  for (int n = 0; n < 4; ++n) {
    int col = wn * 64 + n * 16 + l15;
    float bv = bias[col];
#pragma unroll
    for (int m = 0; m < 4; ++m) {
      int rbase = row0 + wm * 64 + m * 16 + lq * 4;
#pragma unroll
      for (int q = 0; q < 4; ++q) {
        int row = rbase + q;
        if (row < N) {
          float v = fmaxf(acc[m][n][q] + bv, 0.f);
          if (outp) outp[(size_t)row * D + col] = v;
          if (wb) wb[(size_t)row * KT_TOT + col] = f2bf(v);
        }
      }
    }
  }
}

extern "C" void kernel_launch(void* const* d_in, const int* in_sizes, int n_in,
                              void* d_out, int out_size, void* d_ws, size_t ws_size,
                              hipStream_t stream) {
  const float* emb = (const float*)d_in[0];
  const float* W1 = (const float*)d_in[1];
  const float* SL1 = (const float*)d_in[2];
  const float* B1 = (const float*)d_in[3];
  const float* W2 = (const float*)d_in[4];
  const float* SL2 = (const float*)d_in[5];
  const float* B2 = (const float*)d_in[6];
  const int* eidx = (const int*)d_in[7];
  const int* etyp = (const int*)d_in[8];
  const int N = in_sizes[0] / D;
  const int E = in_sizes[8];
  const int* srcp = eidx;
  const int* dstp = eidx + E;
  float* outp = (float*)d_out;

  unsigned short* Abuf = (unsigned short*)d_ws;          // [N][KT_TOT] bf16
  unsigned short* Bt = Abuf + (size_t)N * KT_TOT;        // [D][KT_TOT] bf16

  const long zh_total = (long)N * 128;  // 16B chunks in cols 0..1023
  const int cx_blocks = (int)(((long)N * 32 + 255) / 256);
  const int wc_blocks = (D * KT_TOT + 255) / 256;
  const int sc_blocks = (E + 3) / 4;
  const int gm_blocks = (N + BM - 1) / BM;

  // ---- layer 1 ----
  zero_h<<<2048, 256, 0, stream>>>(Abuf, zh_total);
  cvt_x<<<cx_blocks, 256, 0, stream>>>(emb, Abuf + (KT_TOT - D), N);
  wcvt<<<wc_blocks, 256, 0, stream>>>(W1, SL1, Bt);
  scatter_pk<<<sc_blocks, 256, 0, stream>>>(emb, nullptr, srcp, dstp, etyp, Abuf, E);
  gemm_mfma<<<gm_blocks, 256, 0, stream>>>(Abuf, Bt, B1, nullptr,
                                           Abuf + (KT_TOT - D), N);

  // ---- layer 2 ----
  zero_h<<<2048, 256, 0, stream>>>(Abuf, zh_total);
  wcvt<<<wc_blocks, 256, 0, stream>>>(W2, SL2, Bt);
  scatter_pk<<<sc_blocks, 256, 0, stream>>>(nullptr, Abuf + (KT_TOT - D), srcp,
                                            dstp, etyp, Abuf, E);
  gemm_mfma<<<gm_blocks, 256, 0, stream>>>(Abuf, Bt, B2, outp, nullptr, N);
}

// Round 3
// 365.321 us; speedup vs baseline: 8.5312x; 1.4188x over previous
//
#include <hip/hip_runtime.h>

#define D 128
#define BM 128
#define NREL 8
#define SCAN_BLOCKS 782
#define MPAD (SCAN_BLOCKS * 1024)  // 800768 >= N*8+1

typedef __attribute__((ext_vector_type(8))) short short8;
typedef __attribute__((ext_vector_type(8))) unsigned short ushort8;
typedef __attribute__((ext_vector_type(4))) float f32x4;

typedef const void __attribute__((address_space(1))) gvoid_t;
typedef void __attribute__((address_space(3))) lvoid_t;

__device__ inline unsigned short f2bf(float f) {
  unsigned u = __builtin_bit_cast(unsigned, f);
  u += 0x7FFFu + ((u >> 16) & 1u);
  return (unsigned short)(u >> 16);
}

__device__ inline void gload16(const void* g, void* l) {
  __builtin_amdgcn_global_load_lds((gvoid_t*)g, (lvoid_t*)l, 16, 0, 0);
}

// emb f32 -> xb bf16, compact [N][128]
__global__ __launch_bounds__(256) void cvt_x(const float* __restrict__ x,
                                             unsigned short* __restrict__ dst,
                                             long total /* = N*32 float4 */) {
  long i = (long)blockIdx.x * 256 + threadIdx.x;
  if (i >= total) return;
  float4 v = reinterpret_cast<const float4*>(x)[i];
  unsigned lo = (unsigned)f2bf(v.x) | ((unsigned)f2bf(v.y) << 16);
  unsigned hi = (unsigned)f2bf(v.z) | ((unsigned)f2bf(v.w) << 16);
  reinterpret_cast<uint2*>(dst)[i] = make_uint2(lo, hi);
}

// Btr[r][col][k] = W[r][k][col] (r<8), Btr[8][col][k] = SW[k][col], bf16
__global__ __launch_bounds__(256) void wcvt(const float* __restrict__ W,
                                            const float* __restrict__ SW,
                                            unsigned short* __restrict__ Btr) {
  int idx = blockIdx.x * 256 + threadIdx.x;
  if (idx >= 9 * D * D) return;
  int r = idx >> 14;
  int rem = idx & 16383;
  int col = rem >> 7;
  int k = rem & 127;
  float v = (r < NREL) ? W[((r * D) + k) * D + col] : SW[k * D + col];
  Btr[idx] = f2bf(v);
}

__global__ __launch_bounds__(256) void hist_kernel(const int* __restrict__ dst,
                                                   const int* __restrict__ rel,
                                                   int* __restrict__ counts, int E) {
  int e = blockIdx.x * 256 + threadIdx.x;
  if (e >= E) return;
  atomicAdd(&counts[(dst[e] << 3) | rel[e]], 1);
}

// per-block exclusive scan of 1024 ints; bsum[bid] = block total
__global__ __launch_bounds__(256) void scan1(const int* __restrict__ in,
                                             int* __restrict__ out,
                                             int* __restrict__ bsum) {
  __shared__ int tmp[256];
  int t = threadIdx.x;
  long base = (long)blockIdx.x * 1024 + t * 4;
  int v[4];
  int s = 0;
#pragma unroll
  for (int j = 0; j < 4; ++j) {
    v[j] = in[base + j];
    s += v[j];
  }
  tmp[t] = s;
  __syncthreads();
  for (int off = 1; off < 256; off <<= 1) {
    int x = (t >= off) ? tmp[t - off] : 0;
    __syncthreads();
    tmp[t] += x;
    __syncthreads();
  }
  int run = tmp[t] - s;  // exclusive prefix of this thread's quad
  if (t == 255) bsum[blockIdx.x] = tmp[255];
#pragma unroll
  for (int j = 0; j < 4; ++j) {
    out[base + j] = run;
    run += v[j];
  }
}

// single block: exclusive scan of bsum[nb] in place (nb <= 1024)
__global__ __launch_bounds__(1024) void scan_top(int* __restrict__ bsum, int nb) {
  __shared__ int tmp[1024];
  int t = threadIdx.x;
  int v = (t < nb) ? bsum[t] : 0;
  tmp[t] = v;
  __syncthreads();
  for (int off = 1; off < 1024; off <<= 1) {
    int x = (t >= off) ? tmp[t - off] : 0;
    __syncthreads();
    tmp[t] += x;
    __syncthreads();
  }
  if (t < nb) bsum[t] = tmp[t] - v;
}

__global__ __launch_bounds__(256) void scan_add(int* __restrict__ starts,
                                                int* __restrict__ cursor,
                                                const int* __restrict__ bsum) {
  long base = (long)blockIdx.x * 1024 + threadIdx.x * 4;
  int add = bsum[blockIdx.x];
#pragma unroll
  for (int j = 0; j < 4; ++j) {
    int v = starts[base + j] + add;
    starts[base + j] = v;
    cursor[base + j] = v;
  }
}

__global__ __launch_bounds__(256) void reorder(const int* __restrict__ src,
                                               const int* __restrict__ dst,
                                               const int* __restrict__ rel,
                                               int* __restrict__ cursor,
                                               int* __restrict__ esort, int E) {
  int e = blockIdx.x * 256 + threadIdx.x;
  if (e >= E) return;
  int key = (dst[e] << 3) | rel[e];
  int pos = atomicAdd(&cursor[key], 1);
  esort[pos] = src[e];
}

// Fused: per 128-row block, for r=0..7 gather-aggregate A-tile from CSR
// edges (sorted by (dst,rel)) into LDS, MFMA vs W[r]; r=8 is the self-loop
// (A = xb rows directly). out = relu(sum + bias).
__global__ __launch_bounds__(256) void fused_layer(
    const unsigned short* __restrict__ xb, const int* __restrict__ starts,
    const int* __restrict__ esort, const unsigned short* __restrict__ Btr,
    const float* __restrict__ bias, unsigned short* __restrict__ xout_b,
    float* __restrict__ outf, int N) {
  __shared__ char As[32768];  // 128 rows x 256B, XOR-swizzled
  __shared__ char Bs[32768];

  const int tid = threadIdx.x;
  const int wave = tid >> 6, lane = tid & 63;
  const int wm = wave >> 1, wn = wave & 1;
  const int l15 = lane & 15, lq = lane >> 4;
  const int row0 = blockIdx.x * BM;

  f32x4 acc[4][4];
#pragma unroll
  for (int m = 0; m < 4; ++m)
#pragma unroll
    for (int n = 0; n < 4; ++n)
#pragma unroll
      for (int q = 0; q < 4; ++q) acc[m][n][q] = 0.f;

  for (int r = 0; r < 9; ++r) {
    // stage B tile (W[r] or SW), pre-swizzled source -> linear LDS
    const unsigned short* Bsrc = Btr + r * (D * D);
#pragma unroll
    for (int i = 0; i < 8; ++i) {
      int o = i * 4096 + tid * 16;
      int row = o >> 8, b = o & 255;
      int sb = b ^ ((row & 7) << 4);
      gload16(Bsrc + row * D + (sb >> 1), Bs + o);
    }
    if (r < NREL) {
      // gather-aggregate A-tile: 4 lanes per row, 32 cols each, f32 accum
#pragma unroll
      for (int half = 0; half < 2; ++half) {
        int lr = half * 64 + (tid >> 2);
        int cb = tid & 3;
        int dstn = row0 + lr;
        float a[32];
#pragma unroll
        for (int j = 0; j < 32; ++j) a[j] = 0.f;
        if (dstn < N) {
          int e0 = starts[(dstn << 3) + r];
          int e1 = starts[(dstn << 3) + r + 1];
          for (int e = e0; e < e1; ++e) {
            int s = esort[e];
            const ushort8* p =
                reinterpret_cast<const ushort8*>(xb + (size_t)s * D + cb * 32);
#pragma unroll
            for (int j = 0; j < 4; ++j) {
              ushort8 v = p[j];
#pragma unroll
              for (int k = 0; k < 8; ++k)
                a[j * 8 + k] +=
                    __builtin_bit_cast(float, (unsigned)v[k] << 16);
            }
          }
        }
#pragma unroll
        for (int j = 0; j < 4; ++j) {
          short8 w;
#pragma unroll
          for (int k = 0; k < 8; ++k) w[k] = (short)f2bf(a[j * 8 + k]);
          int b = (cb * 64 + j * 16) ^ ((lr & 7) << 4);
          *reinterpret_cast<short8*>(As + lr * 256 + b) = w;
        }
      }
    } else {
      // self-loop pass: A = xb rows (direct, pre-swizzled source)
#pragma unroll
      for (int i = 0; i < 8; ++i) {
        int o = i * 4096 + tid * 16;
        int row = o >> 8, b = o & 255;
        int grow = row0 + row;
        if (grow >= N) grow = N - 1;
        int sb = b ^ ((row & 7) << 4);
        gload16(xb + (size_t)grow * D + (sb >> 1), As + o);
      }
    }
    __syncthreads();
    // MFMA over K=128 in two half-K subphases (register pressure)
#pragma unroll
    for (int kh = 0; kh < 2; ++kh) {
      short8 af[4][2], bfr[4][2];
#pragma unroll
      for (int m = 0; m < 4; ++m)
#pragma unroll
        for (int k2 = 0; k2 < 2; ++k2) {
          int rr = wm * 64 + m * 16 + l15;
          int b = ((kh * 2 + k2) * 64 + lq * 16) ^ ((rr & 7) << 4);
          af[m][k2] = *reinterpret_cast<const short8*>(As + rr * 256 + b);
        }
#pragma unroll
      for (int n = 0; n < 4; ++n)
#pragma unroll
        for (int k2 = 0; k2 < 2; ++k2) {
          int rr = wn * 64 + n * 16 + l15;
          int b = ((kh * 2 + k2) * 64 + lq * 16) ^ ((rr & 7) << 4);
          bfr[n][k2] = *reinterpret_cast<const short8*>(Bs + rr * 256 + b);
        }
#pragma unroll
      for (int m = 0; m < 4; ++m)
#pragma unroll
        for (int n = 0; n < 4; ++n) {
          acc[m][n] = __builtin_amdgcn_mfma_f32_16x16x32_bf16(
              af[m][0], bfr[n][0], acc[m][n], 0, 0, 0);
          acc[m][n] = __builtin_amdgcn_mfma_f32_16x16x32_bf16(
              af[m][1], bfr[n][1], acc[m][n], 0, 0, 0);
        }
    }
    __syncthreads();
  }

  // epilogue: C/D layout col = lane&15, row = (lane>>4)*4 + reg
#pragma unroll
  for (int n = 0; n < 4; ++n) {
    int col = wn * 64 + n * 16 + l15;
    float bv = bias[col];
#pragma unroll
    for (int m = 0; m < 4; ++m) {
      int rbase = row0 + wm * 64 + m * 16 + lq * 4;
#pragma unroll
      for (int q = 0; q < 4; ++q) {
        int row = rbase + q;
        if (row < N) {
          float v = fmaxf(acc[m][n][q] + bv, 0.f);
          if (outf)
            outf[(size_t)row * D + col] = v;
          else
            xout_b[(size_t)row * D + col] = f2bf(v);
        }
      }
    }
  }
}

extern "C" void kernel_launch(void* const* d_in, const int* in_sizes, int n_in,
                              void* d_out, int out_size, void* d_ws, size_t ws_size,
                              hipStream_t stream) {
  const float* emb = (const float*)d_in[0];
  const float* W1 = (const float*)d_in[1];
  const float* SL1 = (const float*)d_in[2];
  const float* B1 = (const float*)d_in[3];
  const float* W2 = (const float*)d_in[4];
  const float* SL2 = (const float*)d_in[5];
  const float* B2 = (const float*)d_in[6];
  const int* eidx = (const int*)d_in[7];
  const int* etyp = (const int*)d_in[8];
  const int N = in_sizes[0] / D;
  const int E = in_sizes[8];
  const int* srcp = eidx;
  const int* dstp = eidx + E;
  float* outp = (float*)d_out;

  char* w = (char*)d_ws;
  unsigned short* xb0 = (unsigned short*)w;               // N*128 bf16
  unsigned short* xb1 = xb0 + (size_t)N * D;              // N*128 bf16
  unsigned short* Btr1 = xb1 + (size_t)N * D;             // 9*128*128 bf16
  unsigned short* Btr2 = Btr1 + 9 * D * D;
  int* counts = (int*)(Btr2 + 9 * D * D);                 // MPAD ints
  int* starts = counts + MPAD;
  int* cursor = starts + MPAD;
  int* bsum = cursor + MPAD;                              // 1024 ints
  int* esort = bsum + 1024;                               // E ints

  const int eb = (E + 255) / 256;
  const int gm_blocks = (N + BM - 1) / BM;

  // preprocessing (graph structure, shared by both layers)
  hipMemsetAsync(counts, 0, (size_t)MPAD * 4, stream);
  cvt_x<<<(int)(((long)N * 32 + 255) / 256), 256, 0, stream>>>(emb, xb0,
                                                               (long)N * 32);
  wcvt<<<(9 * D * D + 255) / 256, 256, 0, stream>>>(W1, SL1, Btr1);
  wcvt<<<(9 * D * D + 255) / 256, 256, 0, stream>>>(W2, SL2, Btr2);
  hist_kernel<<<eb, 256, 0, stream>>>(dstp, etyp, counts, E);
  scan1<<<SCAN_BLOCKS, 256, 0, stream>>>(counts, starts, bsum);
  scan_top<<<1, 1024, 0, stream>>>(bsum, SCAN_BLOCKS);
  scan_add<<<SCAN_BLOCKS, 256, 0, stream>>>(starts, cursor, bsum);
  reorder<<<eb, 256, 0, stream>>>(srcp, dstp, etyp, cursor, esort, E);

  // layer 1: xb0 -> xb1 (bf16)
  fused_layer<<<gm_blocks, 256, 0, stream>>>(xb0, starts, esort, Btr1, B1, xb1,
                                             nullptr, N);
  // layer 2: xb1 -> outp (f32)
  fused_layer<<<gm_blocks, 256, 0, stream>>>(xb1, starts, esort, Btr2, B2,
                                             nullptr, outp, N);
}